// Round 6
// baseline (89.980 us; speedup 1.0000x reference)
//
#include <hip/hip_runtime.h>
#include <math.h>

#define KTOP 200
#define NPART 32
#define BLOCK 512
#define NHIST 2048
#define CAND_CAP 2048      // pivot aims for ~1100 candidates; fallback if outside [KTOP, CAND_CAP]
#define TLIST_CAP 1024
#define WCAP 256           // exactly KTOP winners ever stored
#define SSTAR 28           // sample order statistic -> ~1100 expected candidates

// d2 exactly as numpy: ((dx*dx + dy*dy) + dz*dz), no fma contraction
__device__ __forceinline__ float d2_ref(float ax, float ay, float az,
                                        float bx, float by, float bz) {
    float dx = __fsub_rn(ax, bx), dy = __fsub_rn(ay, by), dz = __fsub_rn(az, bz);
    return __fadd_rn(__fadd_rn(__fmul_rn(dx, dx), __fmul_rn(dy, dy)), __fmul_rn(dz, dz));
}

__device__ __forceinline__ unsigned key_of(const float* __restrict__ fus, int j,
                                           float vx, float vy, float vz) {
    return __float_as_uint(d2_ref(vx, vy, vz, fus[3*j], fus[3*j+1], fus[3*j+2]));
}

// shape-context bin of rel = p_j - q0, mirroring the reference f32 math
__device__ __forceinline__ int compute_bin(float rx, float ry, float rz) {
    const float TWO_PI_F = (float)6.283185307179586;
    const float PI_F     = (float)3.141592653589793;
    const float XY_W     = (float)(6.283185307179586 / 4.0);
    const float ZY_W     = (float)(3.141592653589793 / 4.0);

    float d2 = __fadd_rn(__fadd_rn(__fmul_rn(rx, rx), __fmul_rn(ry, ry)), __fmul_rn(rz, rz));
    float D  = sqrtf(__fadd_rn(d2, 1e-7f));
    float dist_bin;
    if (D >= 4.0f)      dist_bin = 1.0f;
    else if (D >= 1.0f) dist_bin = 0.0f;
    else                return -1;

    float axy = fmodf(atan2f(ry, rx) + TWO_PI_F, TWO_PI_F);
    float azy = fmodf(atan2f(ry, rz) + TWO_PI_F, PI_F);
    float xyb = floorf(__fdiv_rn(axy, XY_W));
    float zyb = floorf(__fdiv_rn(azy, ZY_W));
    if (!(xyb >= 0.0f && zyb >= 0.0f)) return -1;
    float ab  = xyb * 4.0f + zyb;
    int bin = (int)(dist_bin * 16.0f + ab);
    return bin;
}

__global__ __launch_bounds__(BLOCK, 8)
void shape_context_kernel(const float* __restrict__ veh,
                          const float* __restrict__ fus,
                          float* __restrict__ out,
                          int nfus) {
    const int b   = blockIdx.x;
    const int tid = threadIdx.x;
    const int lane = tid & 63;
    const int wid  = tid >> 6;

    __shared__ unsigned int hist[NHIST];
    __shared__ unsigned long long cand[CAND_CAP];
    __shared__ unsigned long long tlist[TLIST_CAP];
    __shared__ int wlist[WCAP];
    __shared__ unsigned int hist32[NPART];
    __shared__ unsigned int waveTot[BLOCK / 64];
    __shared__ unsigned int waveBase[BLOCK / 64];
    __shared__ unsigned int s_bucket, s_rem, s_bcount;
    __shared__ int s_candCount, s_wcount, s_tcount;
    __shared__ unsigned long long s_minPacked, s_serMin, s_lowBound;

    const float vx = veh[b * 3 + 0], vy = veh[b * 3 + 1], vz = veh[b * 3 + 2];
    const float4* fus4 = (const float4*)fus;
    const int ntrip = nfus >> 2;

    if (tid == 0) { s_minPacked = ~0ull; s_candCount = 0; s_wcount = 0; s_tcount = 0; }
    for (int i = tid; i < NHIST; i += BLOCK) hist[i] = 0;
    if (tid < NPART) hist32[tid] = 0;
    __syncthreads();

    // block-wide: find bucket where cumulative hist count crosses remq
    auto find_bucket = [&](unsigned remq) {
        const int PER = NHIST / BLOCK;  // 4
        int base = tid * PER;
        unsigned c[PER];
        unsigned p = 0;
        #pragma unroll
        for (int i = 0; i < PER; i++) { c[i] = hist[base + i]; p += c[i]; }
        unsigned incl = p;
        #pragma unroll
        for (int d = 1; d < 64; d <<= 1) {
            unsigned n = __shfl_up(incl, d, 64);
            if (lane >= d) incl += n;
        }
        if (lane == 63) waveTot[wid] = incl;
        __syncthreads();
        if (tid == 0) {
            unsigned acc = 0;
            for (int w = 0; w < BLOCK / 64; w++) { waveBase[w] = acc; acc += waveTot[w]; }
        }
        __syncthreads();
        unsigned excl = waveBase[wid] + incl - p;
        if (excl < remq && remq <= excl + p) {  // unique crossing thread
            unsigned cum = excl;
            #pragma unroll
            for (int i = 0; i < PER; i++) {
                if (cum + c[i] >= remq) { s_bucket = base + i; s_rem = remq - cum; s_bcount = c[i]; break; }
                cum += c[i];
            }
        }
        __syncthreads();
    };

    // ---- phase 1: 512-point sample -> coarse pivot bucket ----
    {
        int j = (int)(((long long)tid * nfus) / BLOCK);
        unsigned k = key_of(fus, j, vx, vy, vz);
        atomicAdd(&hist[k >> 21], 1u);
    }
    __syncthreads();
    find_bucket(SSTAR);
    const unsigned Pb = s_bucket + 1;   // accept buckets < Pb  (~2% quantile)
    __syncthreads();

    // ---- phase 2: the single full scan — append below-pivot (key,idx) ----
    for (int m = tid; m < ntrip; m += BLOCK) {
        float4 A = fus4[3 * m], Bq = fus4[3 * m + 1], Cq = fus4[3 * m + 2];
        unsigned k0 = __float_as_uint(d2_ref(vx, vy, vz, A.x,  A.y,  A.z));
        unsigned k1 = __float_as_uint(d2_ref(vx, vy, vz, A.w,  Bq.x, Bq.y));
        unsigned k2 = __float_as_uint(d2_ref(vx, vy, vz, Bq.z, Bq.w, Cq.x));
        unsigned k3 = __float_as_uint(d2_ref(vx, vy, vz, Cq.y, Cq.z, Cq.w));
        int jb = 4 * m;
        if ((k0 >> 21) < Pb) { int pos = atomicAdd(&s_candCount, 1); if (pos < CAND_CAP) cand[pos] = ((unsigned long long)k0 << 32) | (unsigned)(jb + 0); }
        if ((k1 >> 21) < Pb) { int pos = atomicAdd(&s_candCount, 1); if (pos < CAND_CAP) cand[pos] = ((unsigned long long)k1 << 32) | (unsigned)(jb + 1); }
        if ((k2 >> 21) < Pb) { int pos = atomicAdd(&s_candCount, 1); if (pos < CAND_CAP) cand[pos] = ((unsigned long long)k2 << 32) | (unsigned)(jb + 2); }
        if ((k3 >> 21) < Pb) { int pos = atomicAdd(&s_candCount, 1); if (pos < CAND_CAP) cand[pos] = ((unsigned long long)k3 << 32) | (unsigned)(jb + 3); }
    }
    for (int j = (nfus & ~3) + tid; j < nfus; j += BLOCK) {
        unsigned k = key_of(fus, j, vx, vy, vz);
        if ((k >> 21) < Pb) { int pos = atomicAdd(&s_candCount, 1); if (pos < CAND_CAP) cand[pos] = ((unsigned long long)k << 32) | (unsigned)j; }
    }
    __syncthreads();

    const int cnt = s_candCount;   // exact count of keys below pivot
    unsigned rem;

    if (cnt >= KTOP && cnt <= CAND_CAP) {
        // ================= normal path: exact top-200 among cnt candidates =================
        // argmin (stable): u64 min over cand
        unsigned long long lm = ~0ull;
        for (int i = tid; i < cnt; i += BLOCK) lm = min(lm, cand[i]);
        #pragma unroll
        for (int d = 32; d > 0; d >>= 1) {
            unsigned long long o = __shfl_xor(lm, d, 64);
            lm = (o < lm) ? o : lm;
        }
        if (lane == 0) atomicMin(&s_minPacked, lm);

        // candidate histogram on bucket ids
        for (int i = tid; i < NHIST; i += BLOCK) hist[i] = 0;
        __syncthreads();
        for (int i = tid; i < cnt; i += BLOCK) atomicAdd(&hist[(unsigned)(cand[i] >> 53)], 1u);
        __syncthreads();
        find_bucket(KTOP);
        const unsigned T2 = s_bucket;
        rem = s_rem;
        const unsigned bcount = s_bcount;

        if (bcount <= TLIST_CAP) {
            for (int i = tid; i < cnt; i += BLOCK) {
                unsigned bk = (unsigned)(cand[i] >> 53);
                if (bk < T2) {
                    int pos = atomicAdd(&s_wcount, 1);
                    if (pos < WCAP) wlist[pos] = (int)(cand[i] & 0xFFFFFFFFull);
                } else if (bk == T2) {
                    int pos = atomicAdd(&s_tcount, 1);
                    if (pos < TLIST_CAP) tlist[pos] = cand[i];
                }
            }
            __syncthreads();
            const int tc = s_tcount;
            for (int i = tid; i < tc; i += BLOCK) {
                unsigned long long me = tlist[i];
                int rank = 0;
                for (int k2 = 0; k2 < tc; k2++) rank += (tlist[k2] < me) ? 1 : 0;
                if (rank < (int)rem) {
                    int pos = atomicAdd(&s_wcount, 1);
                    if (pos < WCAP) wlist[pos] = (int)(me & 0xFFFFFFFFull);
                }
            }
        } else {
            // rare: huge boundary bucket — rank directly against cand
            for (int i = tid; i < cnt; i += BLOCK) {
                unsigned bk = (unsigned)(cand[i] >> 53);
                if (bk < T2) {
                    int pos = atomicAdd(&s_wcount, 1);
                    if (pos < WCAP) wlist[pos] = (int)(cand[i] & 0xFFFFFFFFull);
                }
            }
            __syncthreads();
            for (int i = tid; i < cnt; i += BLOCK) {
                unsigned long long me = cand[i];
                if ((unsigned)(me >> 53) == T2) {
                    int rank = 0;
                    for (int k2 = 0; k2 < cnt; k2++) {
                        unsigned long long o = cand[k2];
                        rank += ((unsigned)(o >> 53) == T2 && o < me) ? 1 : 0;
                    }
                    if (rank < (int)rem) {
                        int pos = atomicAdd(&s_wcount, 1);
                        if (pos < WCAP) wlist[pos] = (int)(me & 0xFFFFFFFFull);
                    }
                }
            }
        }
        __syncthreads();
    } else {
        // ================= fallback: exact radix-select (reload-based, rare) =================
        if (tid == 0) s_candCount = 0;
        for (int i = tid; i < NHIST; i += BLOCK) hist[i] = 0;
        __syncthreads();
        for (int j = tid; j < nfus; j += BLOCK)
            atomicAdd(&hist[key_of(fus, j, vx, vy, vz) >> 21], 1u);
        __syncthreads();
        find_bucket(KTOP);
        unsigned T = s_bucket;
        rem = s_rem;
        unsigned bcount = s_bcount;
        int shift = 21;

        while (bcount > CAND_CAP && shift > 0) {
            int newshift = (shift > 11) ? (shift - 11) : 0;
            unsigned digmask = (1u << (shift - newshift)) - 1;
            __syncthreads();
            for (int i = tid; i < NHIST; i += BLOCK) hist[i] = 0;
            __syncthreads();
            for (int j = tid; j < nfus; j += BLOCK) {
                unsigned k = key_of(fus, j, vx, vy, vz);
                if ((k >> shift) == T) atomicAdd(&hist[(k >> newshift) & digmask], 1u);
            }
            __syncthreads();
            find_bucket(rem);
            T = (T << (shift - newshift)) | s_bucket;
            rem = s_rem;
            bcount = s_bcount;
            shift = newshift;
        }

        // scan B: winners -> wlist, boundary -> cand; argmin over all selected
        for (int j = tid; j < nfus; j += BLOCK) {
            unsigned k = key_of(fus, j, vx, vy, vz);
            unsigned hi = k >> shift;
            if (hi < T) {
                int pos = atomicAdd(&s_wcount, 1);
                if (pos < WCAP) wlist[pos] = j;
                atomicMin(&s_minPacked, ((unsigned long long)k << 32) | (unsigned)j);
            } else if (hi == T) {
                int pos = atomicAdd(&s_candCount, 1);
                if (pos < CAND_CAP) cand[pos] = ((unsigned long long)k << 32) | (unsigned)j;
                atomicMin(&s_minPacked, ((unsigned long long)k << 32) | (unsigned)j);
            }
        }
        __syncthreads();
        const int fcnt = s_candCount;
        if (fcnt <= CAND_CAP) {
            for (int i = tid; i < fcnt; i += BLOCK) {
                unsigned long long me = cand[i];
                int rank = 0;
                for (int k2 = 0; k2 < fcnt; k2++) rank += (cand[k2] < me) ? 1 : 0;
                if (rank < (int)rem) {
                    int pos = atomicAdd(&s_wcount, 1);
                    if (pos < WCAP) wlist[pos] = (int)(me & 0xFFFFFFFFull);
                }
            }
            __syncthreads();
        } else {
            // pathological (>CAND_CAP identical 32-bit keys at boundary): serial extraction
            const int idx0f = (int)(s_minPacked & 0xFFFFFFFFull);
            const float fq0x = fus[idx0f * 3], fq0y = fus[idx0f * 3 + 1], fq0z = fus[idx0f * 3 + 2];
            if (tid == 0) s_lowBound = 0;
            __syncthreads();
            for (unsigned itx = 0; itx < rem; ++itx) {
                if (tid == 0) s_serMin = ~0ull;
                __syncthreads();
                unsigned long long lowB = s_lowBound;
                unsigned long long lmx = ~0ull;
                for (int j = tid; j < nfus; j += BLOCK) {
                    unsigned k = key_of(fus, j, vx, vy, vz);
                    if ((k >> shift) == T) {
                        unsigned long long p = ((unsigned long long)k << 32) | (unsigned)j;
                        if (p >= lowB && p < lmx) lmx = p;
                    }
                }
                #pragma unroll
                for (int d = 32; d > 0; d >>= 1) {
                    unsigned long long o = __shfl_xor(lmx, d, 64);
                    lmx = (o < lmx) ? o : lmx;
                }
                if (lane == 0) atomicMin(&s_serMin, lmx);
                __syncthreads();
                if (tid == 0) {
                    int jm = (int)(s_serMin & 0xFFFFFFFFull);
                    float fx = fus[jm * 3], fy = fus[jm * 3 + 1], fz = fus[jm * 3 + 2];
                    int bin = compute_bin(__fsub_rn(fx, fq0x), __fsub_rn(fy, fq0y), __fsub_rn(fz, fq0z));
                    if (bin >= 0 && bin < NPART) hist32[bin] += 1u;
                    s_lowBound = s_serMin + 1;
                }
                __syncthreads();
            }
        }
    }

    // ---- common: q0 = stable nearest point; winners -> shape-context bins ----
    const int idx0 = (int)(s_minPacked & 0xFFFFFFFFull);
    const float q0x = fus[idx0 * 3], q0y = fus[idx0 * 3 + 1], q0z = fus[idx0 * 3 + 2];
    {
        int wc = s_wcount; if (wc > WCAP) wc = WCAP;
        for (int i = tid; i < wc; i += BLOCK) {
            int j = wlist[i];
            float fx = fus[3 * j], fy = fus[3 * j + 1], fz = fus[3 * j + 2];
            int bin = compute_bin(__fsub_rn(fx, q0x), __fsub_rn(fy, q0y), __fsub_rn(fz, q0z));
            if (bin >= 0 && bin < NPART) atomicAdd(&hist32[bin], 1u);
        }
    }
    __syncthreads();

    // ---- epilogue (32 lanes of wave 0): counts+1 -> L2-normalize*4 -> softmax ----
    if (tid < NPART) {
        float c = (float)hist32[tid] + 1.0f;
        float ss = __fmul_rn(c, c);
        #pragma unroll
        for (int d = 16; d > 0; d >>= 1) ss += __shfl_xor(ss, d, 64);
        float v = __fmul_rn(__fdiv_rn(c, sqrtf(ss)), 4.0f);
        float mx = v;
        #pragma unroll
        for (int d = 16; d > 0; d >>= 1) mx = fmaxf(mx, __shfl_xor(mx, d, 64));
        float e = expf(v - mx);
        float sum = e;
        #pragma unroll
        for (int d = 16; d > 0; d >>= 1) sum += __shfl_xor(sum, d, 64);
        out[b * NPART + tid] = __fdiv_rn(e, sum);
    }
}

extern "C" void kernel_launch(void* const* d_in, const int* in_sizes, int n_in,
                              void* d_out, int out_size, void* d_ws, size_t ws_size,
                              hipStream_t stream) {
    const float* veh = (const float*)d_in[0];   // (1024, 3)
    const float* fus = (const float*)d_in[1];   // (20000, 3)
    float* out = (float*)d_out;                 // (1024, 32)
    int nveh = in_sizes[0] / 3;
    int nfus = in_sizes[1] / 3;
    shape_context_kernel<<<nveh, BLOCK, 0, stream>>>(veh, fus, out, nfus);
}